// Round 6
// baseline (195.867 us; speedup 1.0000x reference)
//
#include <hip/hip_runtime.h>
#include <hip/hip_bf16.h>

typedef __attribute__((ext_vector_type(4))) float f32x4;
typedef __attribute__((ext_vector_type(8))) short bf16x8;

#define SDIM 256
#define HID 1024
#define ADIM 64
#define MROWS 65536
#define CHUNK 16
#define NCHUNK 128
#define NCH 32768  // BATCH * HID

// ws layout: bbuf2 [0,128M) as [b][t][h]; stb [128M,160M) (dead after gemm1p);
// Sbuf [128M,144M) & Cbuf [144M,160M) alias stb after gemm1p;
// bwb [160M,160.5M); cwb [160.5M,160.625M)
#define WS_STB  134217728ull
#define WS_SBUF 134217728ull
#define WS_CBUF 150994944ull
#define WS_BWB  167772160ull
#define WS_CWB  168296448ull
#define WS_NEED 168427520ull

__device__ __forceinline__ unsigned short f2bf(float f) {
  unsigned int u = __float_as_uint(f);
  u += 0x7FFF + ((u >> 16) & 1);  // RNE
  return (unsigned short)(u >> 16);
}
__device__ __forceinline__ float bf2f(unsigned short h) {
  return __uint_as_float(((unsigned int)h) << 16);
}
__device__ __forceinline__ float fast_exp2(float x) {  // 2^x, full-range
  float r;
  asm volatile("v_exp_f32 %0, %1" : "=v"(r) : "v"(x));
  return r;
}
__device__ __forceinline__ float fast_rcp(float x) {  // ~1ulp, bf16-safe
  float r;
  asm volatile("v_rcp_f32 %0, %1" : "=v"(r) : "v"(x));
  return r;
}
#define LOG2E 1.4426950408889634f

#define GLDS16(gp, lp)                                                        \
  __builtin_amdgcn_global_load_lds(                                           \
      (const __attribute__((address_space(1))) unsigned int*)(gp),            \
      (__attribute__((address_space(3))) unsigned int*)(lp), 16, 0, 0)

// ---------------- pre-convert fp32 -> bf16 (states, B_w, C_w) --------------
#define CVT_SN 16777216  // states floats
#define CVT_BN 262144    // B_w floats
#define CVT_CN 65536     // C_w floats
__global__ __launch_bounds__(256) void k_cvt(
    const float* __restrict__ s, const float* __restrict__ bw,
    const float* __restrict__ cw, unsigned short* __restrict__ sb,
    unsigned short* __restrict__ bwb, unsigned short* __restrict__ cwb) {
  long long f = ((long long)blockIdx.x * 256 + threadIdx.x) * 8;
  const float* src;
  unsigned short* dst;
  long long idx;
  if (f < CVT_SN) { src = s; dst = sb; idx = f; }
  else if (f < CVT_SN + CVT_BN) { src = bw; dst = bwb; idx = f - CVT_SN; }
  else { src = cw; dst = cwb; idx = f - CVT_SN - CVT_BN; }
  float4 a = *reinterpret_cast<const float4*>(src + idx);
  float4 b = *reinterpret_cast<const float4*>(src + idx + 4);
  ushort4 lo, hi;
  lo.x = f2bf(a.x); lo.y = f2bf(a.y); lo.z = f2bf(a.z); lo.w = f2bf(a.w);
  hi.x = f2bf(b.x); hi.y = f2bf(b.y); hi.z = f2bf(b.z); hi.w = f2bf(b.w);
  *reinterpret_cast<ushort4*>(dst + idx) = lo;
  *reinterpret_cast<ushort4*>(dst + idx + 4) = hi;
}

// ---------- K1: b = states @ B_w^T + B_b -> bbuf2[b][t][h] (bf16) ----------
// BM=128 BN=128 BK=64, dbuf + counted vmcnt (round-4 proven structure).
__device__ __forceinline__ void g1_compute(
    const char* bA, const char* bB, f32x4 (&acc)[4][4],
    int wm, int wn, int l15, int g) {
  bf16x8 af[4][2], bfv[4][2];
#pragma unroll
  for (int kk = 0; kk < 2; ++kk) {
    int slotsw = ((kk * 4 + g) ^ (l15 & 7)) * 16;
#pragma unroll
    for (int f = 0; f < 4; ++f) {
      af[f][kk] = *reinterpret_cast<const bf16x8*>(bA + (wm + f * 16 + l15) * 128 + slotsw);
      bfv[f][kk] = *reinterpret_cast<const bf16x8*>(bB + (wn + f * 16 + l15) * 128 + slotsw);
    }
  }
#pragma unroll
  for (int kk = 0; kk < 2; ++kk)
#pragma unroll
    for (int i = 0; i < 4; ++i)
#pragma unroll
      for (int j = 0; j < 4; ++j)
        // swapped operands -> C^T fragments (lane holds 4 consecutive n)
        acc[i][j] = __builtin_amdgcn_mfma_f32_16x16x32_bf16(
            bfv[j][kk], af[i][kk], acc[i][j], 0, 0, 0);
}

__global__ __launch_bounds__(256) void k_gemm1p(
    const unsigned short* __restrict__ sb, const unsigned short* __restrict__ bwb,
    const float* __restrict__ Bb, unsigned short* __restrict__ bout) {
  __shared__ char lds[65536];  // dbuf: [A0|B0|A1|B1] 16K each; epi reuses
  const int tid = threadIdx.x;
  const int wave = tid >> 6, lane = tid & 63;
  const int l15 = lane & 15, g = lane >> 4;
  const int bx = blockIdx.x;
  const int swzb = (bx & 7) * 512 + (bx >> 3);  // bijective XCD swizzle
  const int m0 = (swzb >> 3) * 128, n0 = (swzb & 7) * 128;
  const int wm = (wave >> 1) * 64, wn = (wave & 1) * 64;
  const int srow = lane >> 3;
  const int swslot = (lane & 7) ^ srow;

  f32x4 acc[4][4];
#pragma unroll
  for (int i = 0; i < 4; i++)
#pragma unroll
    for (int j = 0; j < 4; j++) acc[i][j] = (f32x4){0.f, 0.f, 0.f, 0.f};

#define STAGE1(tile, buf)                                                     \
  {                                                                           \
    const int k0b_ = (tile) * 128;                                            \
    char* dA_ = lds + (buf) * 32768;                                          \
    char* dB_ = lds + 16384 + (buf) * 32768;                                  \
    _Pragma("unroll")                                                         \
    for (int p = 0; p < 4; ++p) {                                             \
      int chunk = wave * 4 + p;                                               \
      GLDS16((const char*)sb + ((size_t)(m0 + chunk * 8 + srow) * SDIM) * 2 + \
                 k0b_ + swslot * 16,                                          \
             dA_ + chunk * 1024);                                             \
      GLDS16((const char*)bwb + ((size_t)(n0 + chunk * 8 + srow) * SDIM) * 2 +\
                 k0b_ + swslot * 16,                                          \
             dB_ + chunk * 1024);                                             \
    }                                                                         \
  }

  STAGE1(0, 0);
  for (int t = 0; t < 3; ++t) {
    const int cur = t & 1;
    STAGE1(t + 1, cur ^ 1);
    asm volatile("s_waitcnt vmcnt(8)" ::: "memory");
    __builtin_amdgcn_s_barrier();
    __builtin_amdgcn_sched_barrier(0);
    g1_compute(lds + cur * 32768, lds + 16384 + cur * 32768, acc, wm, wn, l15, g);
    __builtin_amdgcn_s_barrier();
    __builtin_amdgcn_sched_barrier(0);
  }
  asm volatile("s_waitcnt vmcnt(0)" ::: "memory");
  __builtin_amdgcn_s_barrier();
  __builtin_amdgcn_sched_barrier(0);
  g1_compute(lds + 32768, lds + 16384 + 32768, acc, wm, wn, l15, g);
  __builtin_amdgcn_s_barrier();
  __builtin_amdgcn_sched_barrier(0);

  // epilogue: bias + pack, per-wave LDS transpose, coalesced store to bbuf2
  char* wb = lds + wave * 9216;  // 64 rows x 144B
#pragma unroll
  for (int j = 0; j < 4; ++j) {
    float4 bb = *reinterpret_cast<const float4*>(Bb + n0 + wn + j * 16 + g * 4);
#pragma unroll
    for (int i = 0; i < 4; ++i) {
      ushort4 w;
      w.x = f2bf(acc[i][j][0] + bb.x);
      w.y = f2bf(acc[i][j][1] + bb.y);
      w.z = f2bf(acc[i][j][2] + bb.z);
      w.w = f2bf(acc[i][j][3] + bb.w);
      *reinterpret_cast<ushort4*>(wb + (i * 16 + l15) * 144 + j * 32 + g * 8) = w;
    }
  }
#pragma unroll
  for (int tt = 0; tt < 8; ++tt) {
    int ml = (lane >> 3) + tt * 8;
    int4 v = *reinterpret_cast<const int4*>(wb + ml * 144 + (lane & 7) * 16);
    int m = m0 + wm + ml;  // m = t*32 + batch
    size_t dst = ((size_t)(m & 31) * 2048 + (size_t)(m >> 5)) * HID +
                 n0 + wn + (lane & 7) * 8;
    *reinterpret_cast<int4*>(bout + dst) = v;
  }
}

// ------------- K2a: per-chunk partial scan sums (bbuf2 layout) -----------
__global__ __launch_bounds__(256) void k_scan_partial(
    const unsigned short* __restrict__ b2, const float* __restrict__ A_log,
    float* __restrict__ Sbuf) {
  int gid = blockIdx.x * 256 + threadIdx.x;  // 0..NCHUNK*4096-1
  int ch = (gid & 4095) * 8;
  int c = gid >> 12;
  int bb = ch >> 10;
  int hh = ch & 1023;
  float4 al0 = *reinterpret_cast<const float4*>(A_log + hh);
  float4 al1 = *reinterpret_cast<const float4*>(A_log + hh + 4);
  float a[8] = {__expf(al0.x), __expf(al0.y), __expf(al0.z), __expf(al0.w),
                __expf(al1.x), __expf(al1.y), __expf(al1.z), __expf(al1.w)};
  const unsigned short* p = b2 + (size_t)bb * 2097152 + (size_t)c * CHUNK * HID + hh;
  float s[8] = {0.f, 0.f, 0.f, 0.f, 0.f, 0.f, 0.f, 0.f};
#pragma unroll 4
  for (int j = 0; j < CHUNK; ++j) {
    int4 v = *reinterpret_cast<const int4*>(p + (size_t)j * HID);
    unsigned int u[4] = {(unsigned)v.x, (unsigned)v.y, (unsigned)v.z, (unsigned)v.w};
#pragma unroll
    for (int e = 0; e < 4; ++e) {
      s[2 * e]     = fmaf(a[2 * e],     s[2 * e],     __uint_as_float(u[e] << 16));
      s[2 * e + 1] = fmaf(a[2 * e + 1], s[2 * e + 1], __uint_as_float(u[e] & 0xFFFF0000u));
    }
  }
  float4 o0 = {s[0], s[1], s[2], s[3]}, o1 = {s[4], s[5], s[6], s[7]};
  *reinterpret_cast<float4*>(Sbuf + (size_t)c * NCH + ch) = o0;
  *reinterpret_cast<float4*>(Sbuf + (size_t)c * NCH + ch + 4) = o1;
}

// ------------- K2b: carry scan over chunks ----------------
__global__ __launch_bounds__(256) void k_scan_carry(
    const float* __restrict__ Sbuf, const float* __restrict__ A_log,
    float* __restrict__ Cbuf) {
  int ch = blockIdx.x * 256 + threadIdx.x;  // 0..32767
  float aL = __expf(A_log[ch & (HID - 1)] * (float)CHUNK);
  float h = 0.f;
  for (int c = 0; c < NCHUNK; ++c) {
    Cbuf[(size_t)c * NCH + ch] = h;
    h = fmaf(aL, h, Sbuf[(size_t)c * NCH + ch]);
  }
}

// ---- K3 (fused): scan+tanh on the fly + mus GEMM + Gaussian log-prob -----
// Block = one batch x 64 t (= 4 chunks of 16). 1024 blocks x 256 thr.
// LDS double-buffered (one barrier per kt). A reg-staged scan with
// XOR-swizzled ds_write; B via gload_lds with pre-swizzled global source.
__global__ __launch_bounds__(256) void k_gemm2f(
    const unsigned short* __restrict__ b2, const float* __restrict__ actions,
    const unsigned short* __restrict__ cwb, const float* __restrict__ Cb,
    const float* __restrict__ log_std, const float* __restrict__ A_log,
    const float* __restrict__ Cbuf, float* __restrict__ out) {
  __shared__ char lds[32768];  // dbuf {A(8K)|B(8K)} x2
  const int tid = threadIdx.x;
  const int wave = tid >> 6, lane = tid & 63;
  const int l15 = lane & 15, g = lane >> 4;
  const int bq = blockIdx.x;
  const int bb = bq >> 5;          // batch 0..31
  const int t0 = (bq & 31) * 64;   // t-range start
  const int c0 = t0 >> 4;          // global chunk base (CHUNK=16)
  const int wm = wave * 16;
  const int srow = lane >> 3;
  const int swslot = (lane & 7) ^ srow;
  const int sh = tid & 63;  // scan h-col within k-slice
  const int tq = tid >> 6;  // scan t-quarter (16 t each)

  f32x4 acc[4];
#pragma unroll
  for (int j = 0; j < 4; j++) acc[j] = (f32x4){0.f, 0.f, 0.f, 0.f};

  for (int kt = 0; kt < 16; ++kt) {
    char* buf = lds + (kt & 1) * 16384;
    // B slice (64 a-rows x 64 h) via gload_lds, pre-swizzled source
#pragma unroll
    for (int p = 0; p < 2; ++p) {
      int chunk = wave * 2 + p;
      GLDS16((const char*)cwb + ((size_t)(chunk * 8 + srow)) * 2048 +
                 kt * 128 + swslot * 16,
             buf + 8192 + chunk * 1024);
    }
    // A: global load -> scan -> tanh -> swizzled LDS write
    {
      const int hglob = kt * 64 + sh;
      const float a = fast_exp2(A_log[hglob] * LOG2E);
      float hst = Cbuf[(size_t)(c0 + tq) * NCH + bb * 1024 + hglob];
      const unsigned short* src =
          b2 + (size_t)bb * 2097152 + (size_t)(t0 + tq * 16) * HID + hglob;
#pragma unroll
      for (int j = 0; j < 16; ++j) {
        hst = fmaf(a, hst, bf2f(src[(size_t)j * HID]));
        float e = fast_exp2(hst * (2.0f * LOG2E));     // exp(2h)
        float tn = fmaf(-2.0f, fast_rcp(e + 1.0f), 1.0f);  // tanh(h)
        int row = tq * 16 + j;
        *reinterpret_cast<unsigned short*>(
            buf + row * 128 + ((sh * 2) ^ ((row & 7) << 4))) = f2bf(tn);
      }
    }
    __syncthreads();  // single barrier per kt (dbuf)
    bf16x8 af[2], bfv[4][2];
#pragma unroll
    for (int kk = 0; kk < 2; ++kk) {
      int slotsw = ((kk * 4 + g) ^ (l15 & 7)) * 16;
      af[kk] = *reinterpret_cast<const bf16x8*>(buf + (wm + l15) * 128 + slotsw);
#pragma unroll
      for (int f = 0; f < 4; ++f)
        bfv[f][kk] = *reinterpret_cast<const bf16x8*>(
            buf + 8192 + (f * 16 + l15) * 128 + slotsw);
    }
#pragma unroll
    for (int kk = 0; kk < 2; ++kk)
#pragma unroll
      for (int j = 0; j < 4; ++j)
        acc[j] = __builtin_amdgcn_mfma_f32_16x16x32_bf16(
            af[kk], bfv[j][kk], acc[j], 0, 0, 0);
  }
  // fused epilogue: log_pi row-sum over 64 action dims
  float istd[4], cb[4];
#pragma unroll
  for (int j = 0; j < 4; ++j) {
    int n = j * 16 + l15;
    istd[j] = __expf(-log_std[n]);
    cb[j] = Cb[n];
  }
  float sls = 0.f;
  for (int n = 0; n < ADIM; ++n) sls += log_std[n];
  const float cterm = -32.0f * 1.8378770664093453f - sls;
  const int rb = wm + g * 4;
#pragma unroll
  for (int r = 0; r < 4; ++r) {
    int rl = rb + r;                 // local t-row (0..63)
    int mo = (t0 + rl) * 32 + bb;    // original row index [L,B]
    float ss = 0.f;
#pragma unroll
    for (int j = 0; j < 4; ++j) {
      int n = j * 16 + l15;
      float mu = acc[j][r] + cb[j];
      float d = (actions[(size_t)mo * ADIM + n] - mu) * istd[j];
      ss = fmaf(d, d, ss);
    }
    ss += __shfl_xor(ss, 1);
    ss += __shfl_xor(ss, 2);
    ss += __shfl_xor(ss, 4);
    ss += __shfl_xor(ss, 8);
    if (l15 == 0) out[mo] = cterm - 0.5f * ss;
  }
}

// ===================== fallback (round-1 proven, OLD [m][h] layout) ========
__device__ __forceinline__ int swz_fb(int row, int byteInRow) {
  int slot = (byteInRow >> 4) & 3;
  slot = (slot + (row >> 1)) & 3;
  return row * 64 + slot * 16 + (byteInRow & 15);
}

__global__ __launch_bounds__(256) void k_gemm1_fb(
    const float* __restrict__ states, const float* __restrict__ Bw,
    const float* __restrict__ Bb, unsigned short* __restrict__ bout) {
  __shared__ char ldsmem[2 * 128 * 64];
  char* ldsA = ldsmem;
  char* ldsB = ldsmem + 128 * 64;
  const int tid = threadIdx.x;
  const int bx = blockIdx.x;
  const int mt = bx >> 3, nt = bx & 7;
  const int m0 = mt * 128, n0 = nt * 128;
  const int wave = tid >> 6, lane = tid & 63;
  const int wm = (wave >> 1) * 64, wn = (wave & 1) * 64;
  const int sr = tid >> 3;
  const int sc = tid & 7;
  f32x4 acc[4][4];
  for (int i = 0; i < 4; i++)
    for (int j = 0; j < 4; j++) acc[i][j] = (f32x4){0.f, 0.f, 0.f, 0.f};
  const int l15 = lane & 15;
  const int slot16 = (lane >> 4) * 16;
  int offA[4], offB[4], wrOff[4];
  for (int f = 0; f < 4; ++f) {
    offA[f] = swz_fb(wm + f * 16 + l15, slot16);
    offB[f] = swz_fb(wn + f * 16 + l15, slot16);
  }
  for (int p = 0; p < 4; ++p) wrOff[p] = swz_fb(sr + p * 32, sc * 8);
  for (int kt = 0; kt < 8; ++kt) {
    const int k0 = kt * 32;
    for (int p = 0; p < 4; ++p) {
      int r = sr + p * 32;
      float4 va = *reinterpret_cast<const float4*>(states + (size_t)(m0 + r) * SDIM + k0 + sc * 4);
      float4 vb = *reinterpret_cast<const float4*>(Bw + (size_t)(n0 + r) * SDIM + k0 + sc * 4);
      ushort4 wa, wb2;
      wa.x = f2bf(va.x); wa.y = f2bf(va.y); wa.z = f2bf(va.z); wa.w = f2bf(va.w);
      wb2.x = f2bf(vb.x); wb2.y = f2bf(vb.y); wb2.z = f2bf(vb.z); wb2.w = f2bf(vb.w);
      *reinterpret_cast<ushort4*>(ldsA + wrOff[p]) = wa;
      *reinterpret_cast<ushort4*>(ldsB + wrOff[p]) = wb2;
    }
    __syncthreads();
    bf16x8 af[4], bfv[4];
    for (int f = 0; f < 4; ++f) {
      af[f] = *reinterpret_cast<const bf16x8*>(ldsA + offA[f]);
      bfv[f] = *reinterpret_cast<const bf16x8*>(ldsB + offB[f]);
    }
    for (int i = 0; i < 4; ++i)
      for (int j = 0; j < 4; ++j)
        acc[i][j] = __builtin_amdgcn_mfma_f32_16x16x32_bf16(af[i], bfv[j], acc[i][j], 0, 0, 0);
    __syncthreads();
  }
  const int colg = n0 + wn + l15;
  const int rowg = m0 + wm + (lane >> 4) * 4;
  for (int j = 0; j < 4; ++j) {
    float bbv = Bb[colg + j * 16];
    for (int i = 0; i < 4; ++i)
      for (int r = 0; r < 4; ++r) {
        int row = rowg + i * 16 + r;
        bout[(size_t)row * HID + colg + j * 16] = f2bf(acc[i][j][r] + bbv);
      }
  }
}

__global__ __launch_bounds__(256) void k_scan_partial_fb(
    const unsigned short* __restrict__ b, const float* __restrict__ A_log,
    float* __restrict__ Sbuf) {
  int gid = blockIdx.x * 256 + threadIdx.x;
  int ch = (gid & 4095) * 8;
  int c = gid >> 12;
  float4 al0 = *reinterpret_cast<const float4*>(A_log + (ch & (HID - 1)));
  float4 al1 = *reinterpret_cast<const float4*>(A_log + (ch & (HID - 1)) + 4);
  float a[8] = {__expf(al0.x), __expf(al0.y), __expf(al0.z), __expf(al0.w),
                __expf(al1.x), __expf(al1.y), __expf(al1.z), __expf(al1.w)};
  const unsigned short* p = b + (size_t)c * CHUNK * NCH + ch;
  float s[8] = {0.f, 0.f, 0.f, 0.f, 0.f, 0.f, 0.f, 0.f};
#pragma unroll 4
  for (int j = 0; j < CHUNK; ++j) {
    int4 v = *reinterpret_cast<const int4*>(p + (size_t)j * NCH);
    unsigned int u[4] = {(unsigned)v.x, (unsigned)v.y, (unsigned)v.z, (unsigned)v.w};
#pragma unroll
    for (int e = 0; e < 4; ++e) {
      s[2 * e]     = fmaf(a[2 * e],     s[2 * e],     __uint_as_float(u[e] << 16));
      s[2 * e + 1] = fmaf(a[2 * e + 1], s[2 * e + 1], __uint_as_float(u[e] & 0xFFFF0000u));
    }
  }
  float4 o0 = {s[0], s[1], s[2], s[3]}, o1 = {s[4], s[5], s[6], s[7]};
  *reinterpret_cast<float4*>(Sbuf + (size_t)c * NCH + ch) = o0;
  *reinterpret_cast<float4*>(Sbuf + (size_t)c * NCH + ch + 4) = o1;
}

__global__ __launch_bounds__(256) void k_scan_final_fb(
    unsigned short* __restrict__ b, const float* __restrict__ A_log,
    const float* __restrict__ Cbuf) {
  int gid = blockIdx.x * 256 + threadIdx.x;
  int ch = (gid & 4095) * 8;
  int c = gid >> 12;
  float4 al0 = *reinterpret_cast<const float4*>(A_log + (ch & (HID - 1)));
  float4 al1 = *reinterpret_cast<const float4*>(A_log + (ch & (HID - 1)) + 4);
  float a[8] = {__expf(al0.x), __expf(al0.y), __expf(al0.z), __expf(al0.w),
                __expf(al1.x), __expf(al1.y), __expf(al1.z), __expf(al1.w)};
  unsigned short* p = b + (size_t)c * CHUNK * NCH + ch;
  float4 h0 = *reinterpret_cast<const float4*>(Cbuf + (size_t)c * NCH + ch);
  float4 h1 = *reinterpret_cast<const float4*>(Cbuf + (size_t)c * NCH + ch + 4);
  float h[8] = {h0.x, h0.y, h0.z, h0.w, h1.x, h1.y, h1.z, h1.w};
#pragma unroll 2
  for (int j = 0; j < CHUNK; ++j) {
    int4 v = *reinterpret_cast<const int4*>(p + (size_t)j * NCH);
    unsigned int u[4] = {(unsigned)v.x, (unsigned)v.y, (unsigned)v.z, (unsigned)v.w};
    unsigned short ob[8];
#pragma unroll
    for (int e = 0; e < 8; ++e) {
      unsigned int bits = (e & 1) ? (u[e >> 1] & 0xFFFF0000u) : (u[e >> 1] << 16);
      h[e] = fmaf(a[e], h[e], __uint_as_float(bits));
      float ex = __expf(2.0f * h[e]);
      ob[e] = f2bf(1.0f - 2.0f / (ex + 1.0f));
    }
    int4 o;
    o.x = (int)((unsigned)ob[0] | ((unsigned)ob[1] << 16));
    o.y = (int)((unsigned)ob[2] | ((unsigned)ob[3] << 16));
    o.z = (int)((unsigned)ob[4] | ((unsigned)ob[5] << 16));
    o.w = (int)((unsigned)ob[6] | ((unsigned)ob[7] << 16));
    *reinterpret_cast<int4*>(p + (size_t)j * NCH) = o;
  }
}

__global__ __launch_bounds__(256) void k_gemm2_fb(
    const unsigned short* __restrict__ hbuf, const float* __restrict__ actions,
    const float* __restrict__ Cw, const float* __restrict__ Cb,
    const float* __restrict__ log_std, float* __restrict__ out) {
  __shared__ char ldsmem[128 * 64 + 64 * 64];
  char* ldsA = ldsmem;
  char* ldsB = ldsmem + 128 * 64;
  const int tid = threadIdx.x;
  const int m0 = blockIdx.x * 128;
  const int wave = tid >> 6, lane = tid & 63;
  const int wrow = wave * 32;
  const int l15 = lane & 15;
  const int slot16 = (lane >> 4) * 16;
  f32x4 acc[2][4];
  for (int i = 0; i < 2; i++)
    for (int j = 0; j < 4; j++) acc[i][j] = (f32x4){0.f, 0.f, 0.f, 0.f};
  const int cA = tid & 3, rA = tid >> 2;
  const int cB = tid & 7, rB = tid >> 3;
  int offA[2], offB[4], wrA[2], wrB[2];
  for (int f = 0; f < 2; ++f) offA[f] = swz_fb(wrow + f * 16 + l15, slot16);
  for (int f = 0; f < 4; ++f) offB[f] = swz_fb(f * 16 + l15, slot16);
  for (int p = 0; p < 2; ++p) wrA[p] = swz_fb(rA + p * 64, cA * 16);
  for (int p = 0; p < 2; ++p) wrB[p] = swz_fb(rB + p * 32, cB * 8);
  for (int kt = 0; kt < 32; ++kt) {
    int k0 = kt * 32;
    for (int p = 0; p < 2; ++p) {
      int r = rA + p * 64;
      int4 v = *reinterpret_cast<const int4*>(hbuf + (size_t)(m0 + r) * HID + k0 + cA * 8);
      *reinterpret_cast<int4*>(ldsA + wrA[p]) = v;
    }
    for (int p = 0; p < 2; ++p) {
      int r = rB + p * 32;
      float4 v = *reinterpret_cast<const float4*>(Cw + (size_t)r * HID + k0 + cB * 4);
      ushort4 w;
      w.x = f2bf(v.x); w.y = f2bf(v.y); w.z = f2bf(v.z); w.w = f2bf(v.w);
      *reinterpret_cast<ushort4*>(ldsB + wrB[p]) = w;
    }
    __syncthreads();
    bf16x8 af[2], bfv[4];
    for (int f = 0; f < 2; ++f) af[f] = *reinterpret_cast<const bf16x8*>(ldsA + offA[f]);
    for (int f = 0; f < 4; ++f) bfv[f] = *reinterpret_cast<const bf16x8*>(ldsB + offB[f]);
    for (int i = 0; i < 2; ++i)
      for (int j = 0; j < 4; ++j)
        acc[i][j] = __builtin_amdgcn_mfma_f32_16x16x32_bf16(af[i], bfv[j], acc[i][j], 0, 0, 0);
    __syncthreads();
  }
  float istd[4], cb[4];
  for (int j = 0; j < 4; ++j) {
    int n = j * 16 + l15;
    istd[j] = __expf(-log_std[n]);
    cb[j] = Cb[n];
  }
  float sls = 0.f;
  for (int n = 0; n < 64; ++n) sls += log_std[n];
  const float cterm = -32.0f * 1.8378770664093453f - sls;
  const int rbase = m0 + wrow + (lane >> 4) * 4;
  for (int i = 0; i < 2; ++i)
    for (int r = 0; r < 4; ++r) {
      int row = rbase + i * 16 + r;
      float ss = 0.f;
      for (int j = 0; j < 4; ++j) {
        int n = j * 16 + l15;
        float mu = acc[i][j][r] + cb[j];
        float d = (actions[(size_t)row * ADIM + n] - mu) * istd[j];
        ss = fmaf(d, d, ss);
      }
      ss += __shfl_xor(ss, 1);
      ss += __shfl_xor(ss, 2);
      ss += __shfl_xor(ss, 4);
      ss += __shfl_xor(ss, 8);
      if (l15 == 0) out[row] = cterm - 0.5f * ss;
    }
}

extern "C" void kernel_launch(void* const* d_in, const int* in_sizes, int n_in,
                              void* d_out, int out_size, void* d_ws, size_t ws_size,
                              hipStream_t stream) {
  const float* states  = (const float*)d_in[0];
  const float* actions = (const float*)d_in[1];
  const float* A_log   = (const float*)d_in[2];
  const float* B_w     = (const float*)d_in[3];
  const float* B_b     = (const float*)d_in[4];
  const float* C_w     = (const float*)d_in[5];
  const float* C_b     = (const float*)d_in[6];
  const float* log_std = (const float*)d_in[7];
  float* out = (float*)d_out;
  char* ws = (char*)d_ws;

  unsigned short* bbuf = (unsigned short*)ws;
  float* Sbuf = (float*)(ws + WS_SBUF);
  float* Cbuf = (float*)(ws + WS_CBUF);
  const int scan_grid = NCHUNK * 4096 / 256;  // 2048 blocks

  if (ws_size >= WS_NEED) {
    unsigned short* stb = (unsigned short*)(ws + WS_STB);
    unsigned short* bwb = (unsigned short*)(ws + WS_BWB);
    unsigned short* cwb = (unsigned short*)(ws + WS_CWB);
    k_cvt<<<8352, 256, 0, stream>>>(states, B_w, C_w, stb, bwb, cwb);
    k_gemm1p<<<4096, 256, 0, stream>>>(stb, bwb, B_b, bbuf);
    k_scan_partial<<<scan_grid, 256, 0, stream>>>(bbuf, A_log, Sbuf);
    k_scan_carry<<<128, 256, 0, stream>>>(Sbuf, A_log, Cbuf);
    k_gemm2f<<<1024, 256, 0, stream>>>(bbuf, actions, cwb, C_b, log_std, A_log,
                                       Cbuf, out);
  } else {
    k_gemm1_fb<<<4096, 256, 0, stream>>>(states, B_w, B_b, bbuf);
    k_scan_partial_fb<<<scan_grid, 256, 0, stream>>>(bbuf, A_log, Sbuf);
    k_scan_carry<<<128, 256, 0, stream>>>(Sbuf, A_log, Cbuf);
    k_scan_final_fb<<<scan_grid, 256, 0, stream>>>(bbuf, A_log, Cbuf);
    k_gemm2_fb<<<512, 256, 0, stream>>>(bbuf, actions, C_w, C_b, log_std, out);
  }
}

// Round 7
// 145.831 us; speedup vs baseline: 1.3431x; 1.3431x over previous
//
#include <hip/hip_runtime.h>
#include <hip/hip_bf16.h>

typedef __attribute__((ext_vector_type(4))) float f32x4;
typedef __attribute__((ext_vector_type(8))) short bf16x8;

#define SDIM 256
#define HID 1024
#define ADIM 64
#define MROWS 65536
#define CHUNK 16
#define NCHUNK 128
#define NCH 32768  // BATCH * HID

// ws layout: bbuf2 [0,128M) as [b][t][h]; stb [128M,160M) (dead after gemm1p);
// Sbuf [128M,144M) & Cbuf [144M,160M) alias stb after gemm1p;
// bwb [160M,160.5M); cwb [160.5M,160.625M)
#define WS_STB  134217728ull
#define WS_SBUF 134217728ull
#define WS_CBUF 150994944ull
#define WS_BWB  167772160ull
#define WS_CWB  168296448ull
#define WS_NEED 168427520ull

__device__ __forceinline__ unsigned short f2bf(float f) {
  unsigned int u = __float_as_uint(f);
  u += 0x7FFF + ((u >> 16) & 1);  // RNE
  return (unsigned short)(u >> 16);
}
__device__ __forceinline__ float bf2f(unsigned short h) {
  return __uint_as_float(((unsigned int)h) << 16);
}
__device__ __forceinline__ float fast_exp2(float x) {  // 2^x, full-range
  float r;
  asm volatile("v_exp_f32 %0, %1" : "=v"(r) : "v"(x));
  return r;
}
__device__ __forceinline__ float fast_rcp(float x) {  // ~1ulp, bf16-safe
  float r;
  asm volatile("v_rcp_f32 %0, %1" : "=v"(r) : "v"(x));
  return r;
}
#define LOG2E 1.4426950408889634f

#define GLDS16(gp, lp)                                                        \
  __builtin_amdgcn_global_load_lds(                                           \
      (const __attribute__((address_space(1))) unsigned int*)(gp),            \
      (__attribute__((address_space(3))) unsigned int*)(lp), 16, 0, 0)

// ---------------- pre-convert fp32 -> bf16 (states, B_w, C_w) --------------
#define CVT_SN 16777216  // states floats
#define CVT_BN 262144    // B_w floats
#define CVT_CN 65536     // C_w floats
__global__ __launch_bounds__(256) void k_cvt(
    const float* __restrict__ s, const float* __restrict__ bw,
    const float* __restrict__ cw, unsigned short* __restrict__ sb,
    unsigned short* __restrict__ bwb, unsigned short* __restrict__ cwb) {
  long long f = ((long long)blockIdx.x * 256 + threadIdx.x) * 8;
  const float* src;
  unsigned short* dst;
  long long idx;
  if (f < CVT_SN) { src = s; dst = sb; idx = f; }
  else if (f < CVT_SN + CVT_BN) { src = bw; dst = bwb; idx = f - CVT_SN; }
  else { src = cw; dst = cwb; idx = f - CVT_SN - CVT_BN; }
  float4 a = *reinterpret_cast<const float4*>(src + idx);
  float4 b = *reinterpret_cast<const float4*>(src + idx + 4);
  ushort4 lo, hi;
  lo.x = f2bf(a.x); lo.y = f2bf(a.y); lo.z = f2bf(a.z); lo.w = f2bf(a.w);
  hi.x = f2bf(b.x); hi.y = f2bf(b.y); hi.z = f2bf(b.z); hi.w = f2bf(b.w);
  *reinterpret_cast<ushort4*>(dst + idx) = lo;
  *reinterpret_cast<ushort4*>(dst + idx + 4) = hi;
}

// ---------- K1: b = states @ B_w^T + B_b -> bbuf2[b][t][h] (bf16) ----------
// BM=128 BN=128 BK=64, dbuf + counted vmcnt (round-4 proven structure).
__device__ __forceinline__ void g1_compute(
    const char* bA, const char* bB, f32x4 (&acc)[4][4],
    int wm, int wn, int l15, int g) {
  bf16x8 af[4][2], bfv[4][2];
#pragma unroll
  for (int kk = 0; kk < 2; ++kk) {
    int slotsw = ((kk * 4 + g) ^ (l15 & 7)) * 16;
#pragma unroll
    for (int f = 0; f < 4; ++f) {
      af[f][kk] = *reinterpret_cast<const bf16x8*>(bA + (wm + f * 16 + l15) * 128 + slotsw);
      bfv[f][kk] = *reinterpret_cast<const bf16x8*>(bB + (wn + f * 16 + l15) * 128 + slotsw);
    }
  }
#pragma unroll
  for (int kk = 0; kk < 2; ++kk)
#pragma unroll
    for (int i = 0; i < 4; ++i)
#pragma unroll
      for (int j = 0; j < 4; ++j)
        // swapped operands -> C^T fragments (lane holds 4 consecutive n)
        acc[i][j] = __builtin_amdgcn_mfma_f32_16x16x32_bf16(
            bfv[j][kk], af[i][kk], acc[i][j], 0, 0, 0);
}

__global__ __launch_bounds__(256) void k_gemm1p(
    const unsigned short* __restrict__ sb, const unsigned short* __restrict__ bwb,
    const float* __restrict__ Bb, unsigned short* __restrict__ bout) {
  __shared__ char lds[65536];  // dbuf: [A0|B0|A1|B1] 16K each; epi reuses
  const int tid = threadIdx.x;
  const int wave = tid >> 6, lane = tid & 63;
  const int l15 = lane & 15, g = lane >> 4;
  const int bx = blockIdx.x;
  const int swzb = (bx & 7) * 512 + (bx >> 3);  // bijective XCD swizzle
  const int m0 = (swzb >> 3) * 128, n0 = (swzb & 7) * 128;
  const int wm = (wave >> 1) * 64, wn = (wave & 1) * 64;
  const int srow = lane >> 3;
  const int swslot = (lane & 7) ^ srow;

  f32x4 acc[4][4];
#pragma unroll
  for (int i = 0; i < 4; i++)
#pragma unroll
    for (int j = 0; j < 4; j++) acc[i][j] = (f32x4){0.f, 0.f, 0.f, 0.f};

#define STAGE1(tile, buf)                                                     \
  {                                                                           \
    const int k0b_ = (tile) * 128;                                            \
    char* dA_ = lds + (buf) * 32768;                                          \
    char* dB_ = lds + 16384 + (buf) * 32768;                                  \
    _Pragma("unroll")                                                         \
    for (int p = 0; p < 4; ++p) {                                             \
      int chunk = wave * 4 + p;                                               \
      GLDS16((const char*)sb + ((size_t)(m0 + chunk * 8 + srow) * SDIM) * 2 + \
                 k0b_ + swslot * 16,                                          \
             dA_ + chunk * 1024);                                             \
      GLDS16((const char*)bwb + ((size_t)(n0 + chunk * 8 + srow) * SDIM) * 2 +\
                 k0b_ + swslot * 16,                                          \
             dB_ + chunk * 1024);                                             \
    }                                                                         \
  }

  STAGE1(0, 0);
  for (int t = 0; t < 3; ++t) {
    const int cur = t & 1;
    STAGE1(t + 1, cur ^ 1);
    asm volatile("s_waitcnt vmcnt(8)" ::: "memory");
    __builtin_amdgcn_s_barrier();
    __builtin_amdgcn_sched_barrier(0);
    g1_compute(lds + cur * 32768, lds + 16384 + cur * 32768, acc, wm, wn, l15, g);
    __builtin_amdgcn_s_barrier();
    __builtin_amdgcn_sched_barrier(0);
  }
  asm volatile("s_waitcnt vmcnt(0)" ::: "memory");
  __builtin_amdgcn_s_barrier();
  __builtin_amdgcn_sched_barrier(0);
  g1_compute(lds + 32768, lds + 16384 + 32768, acc, wm, wn, l15, g);
  __builtin_amdgcn_s_barrier();
  __builtin_amdgcn_sched_barrier(0);

  // epilogue: bias + pack, per-wave LDS transpose, coalesced store to bbuf2
  char* wb = lds + wave * 9216;  // 64 rows x 144B
#pragma unroll
  for (int j = 0; j < 4; ++j) {
    float4 bb = *reinterpret_cast<const float4*>(Bb + n0 + wn + j * 16 + g * 4);
#pragma unroll
    for (int i = 0; i < 4; ++i) {
      ushort4 w;
      w.x = f2bf(acc[i][j][0] + bb.x);
      w.y = f2bf(acc[i][j][1] + bb.y);
      w.z = f2bf(acc[i][j][2] + bb.z);
      w.w = f2bf(acc[i][j][3] + bb.w);
      *reinterpret_cast<ushort4*>(wb + (i * 16 + l15) * 144 + j * 32 + g * 8) = w;
    }
  }
#pragma unroll
  for (int tt = 0; tt < 8; ++tt) {
    int ml = (lane >> 3) + tt * 8;
    int4 v = *reinterpret_cast<const int4*>(wb + ml * 144 + (lane & 7) * 16);
    int m = m0 + wm + ml;  // m = t*32 + batch
    size_t dst = ((size_t)(m & 31) * 2048 + (size_t)(m >> 5)) * HID +
                 n0 + wn + (lane & 7) * 8;
    *reinterpret_cast<int4*>(bout + dst) = v;
  }
}

// ------------- K2a: per-chunk partial scan sums (bbuf2 layout) -----------
__global__ __launch_bounds__(256) void k_scan_partial(
    const unsigned short* __restrict__ b2, const float* __restrict__ A_log,
    float* __restrict__ Sbuf) {
  int gid = blockIdx.x * 256 + threadIdx.x;  // 0..NCHUNK*4096-1
  int ch = (gid & 4095) * 8;
  int c = gid >> 12;
  int bb = ch >> 10;
  int hh = ch & 1023;
  float4 al0 = *reinterpret_cast<const float4*>(A_log + hh);
  float4 al1 = *reinterpret_cast<const float4*>(A_log + hh + 4);
  float a[8] = {__expf(al0.x), __expf(al0.y), __expf(al0.z), __expf(al0.w),
                __expf(al1.x), __expf(al1.y), __expf(al1.z), __expf(al1.w)};
  const unsigned short* p = b2 + (size_t)bb * 2097152 + (size_t)c * CHUNK * HID + hh;
  float s[8] = {0.f, 0.f, 0.f, 0.f, 0.f, 0.f, 0.f, 0.f};
#pragma unroll 4
  for (int j = 0; j < CHUNK; ++j) {
    int4 v = *reinterpret_cast<const int4*>(p + (size_t)j * HID);
    unsigned int u[4] = {(unsigned)v.x, (unsigned)v.y, (unsigned)v.z, (unsigned)v.w};
#pragma unroll
    for (int e = 0; e < 4; ++e) {
      s[2 * e]     = fmaf(a[2 * e],     s[2 * e],     __uint_as_float(u[e] << 16));
      s[2 * e + 1] = fmaf(a[2 * e + 1], s[2 * e + 1], __uint_as_float(u[e] & 0xFFFF0000u));
    }
  }
  float4 o0 = {s[0], s[1], s[2], s[3]}, o1 = {s[4], s[5], s[6], s[7]};
  *reinterpret_cast<float4*>(Sbuf + (size_t)c * NCH + ch) = o0;
  *reinterpret_cast<float4*>(Sbuf + (size_t)c * NCH + ch + 4) = o1;
}

// ------------- K2b: carry scan over chunks ----------------
__global__ __launch_bounds__(256) void k_scan_carry(
    const float* __restrict__ Sbuf, const float* __restrict__ A_log,
    float* __restrict__ Cbuf) {
  int ch = blockIdx.x * 256 + threadIdx.x;  // 0..32767
  float aL = __expf(A_log[ch & (HID - 1)] * (float)CHUNK);
  float h = 0.f;
  for (int c = 0; c < NCHUNK; ++c) {
    Cbuf[(size_t)c * NCH + ch] = h;
    h = fmaf(aL, h, Sbuf[(size_t)c * NCH + ch]);
  }
}

// ---- K3 (fused): scan+tanh on the fly + mus GEMM + Gaussian log-prob -----
// Block = one batch x 64 t (= 4 chunks of 16). 1024 blocks x 256 thr.
// Triple-buffered LDS (16KB each), one raw barrier per kt, batch-of-16
// register prefetch of the scan column one kt ahead (MLP fix).
__global__ __launch_bounds__(256) void k_gemm2f(
    const unsigned short* __restrict__ b2, const float* __restrict__ actions,
    const unsigned short* __restrict__ cwb, const float* __restrict__ Cb,
    const float* __restrict__ log_std, const float* __restrict__ A_log,
    const float* __restrict__ Cbuf, float* __restrict__ out) {
  __shared__ char lds[49152];  // 3 bufs x {A(8K)|B(8K)}
  const int tid = threadIdx.x;
  const int wave = tid >> 6, lane = tid & 63;
  const int l15 = lane & 15, g = lane >> 4;
  const int bq = blockIdx.x;
  const int bb = bq >> 5;          // batch 0..31
  const int t0 = (bq & 31) * 64;   // t-range start
  const int c0 = t0 >> 4;          // global chunk base (CHUNK=16)
  const int wm = wave * 16;
  const int srow = lane >> 3;
  const int swslot = (lane & 7) ^ srow;
  const int sh = tid & 63;  // scan h-col within k-slice
  const int tq = tid >> 6;  // scan t-quarter (16 t each)

  const unsigned short* srcBase =
      b2 + (size_t)bb * 2097152 + (size_t)(t0 + tq * 16) * HID;
  const float* cbBase = Cbuf + (size_t)(c0 + tq) * NCH + bb * 1024;

  f32x4 acc[4];
#pragma unroll
  for (int j = 0; j < 4; j++) acc[j] = (f32x4){0.f, 0.f, 0.f, 0.f};

  unsigned short va[16];
  float a_cur, h_cur, a_nxt = 0.f, h_nxt = 0.f;
  // prologue: prefetch kt=0 (B DMA into buf0, scan column into regs)
  {
#pragma unroll
    for (int p = 0; p < 2; ++p) {
      int chunk = wave * 2 + p;
      GLDS16((const char*)cwb + ((size_t)(chunk * 8 + srow)) * 2048 +
                 swslot * 16,
             lds + 8192 + chunk * 1024);
    }
    a_cur = A_log[sh];
    h_cur = cbBase[sh];
#pragma unroll
    for (int j = 0; j < 16; ++j) va[j] = srcBase[(size_t)j * HID + sh];
  }

#pragma unroll
  for (int kt = 0; kt < 16; ++kt) {
    char* buf = lds + (kt % 3) * 16384;
    // scan chain on registers (va = column kt), tanh, swizzled ds_write
    {
      float a = fast_exp2(a_cur * LOG2E);
      float hst = h_cur;
#pragma unroll
      for (int j = 0; j < 16; ++j) {
        hst = fmaf(a, hst, bf2f(va[j]));
        float e = fast_exp2(hst * (2.0f * LOG2E));      // exp(2h)
        float tn = fmaf(-2.0f, fast_rcp(e + 1.0f), 1.0f);  // tanh(h)
        int row = tq * 16 + j;
        *reinterpret_cast<unsigned short*>(
            buf + row * 128 + ((sh * 2) ^ ((row & 7) << 4))) = f2bf(tn);
      }
    }
    // prefetch kt+1 (B DMA -> third buffer; scan column -> regs)
    if (kt < 15) {
      char* nbuf = lds + ((kt + 1) % 3) * 16384;
#pragma unroll
      for (int p = 0; p < 2; ++p) {
        int chunk = wave * 2 + p;
        GLDS16((const char*)cwb + ((size_t)(chunk * 8 + srow)) * 2048 +
                   (kt + 1) * 128 + swslot * 16,
               nbuf + 8192 + chunk * 1024);
      }
      const int hg2 = (kt + 1) * 64 + sh;
      a_nxt = A_log[hg2];
      h_nxt = cbBase[hg2];
#pragma unroll
      for (int j = 0; j < 16; ++j) va[j] = srcBase[(size_t)j * HID + hg2];
    }
    __builtin_amdgcn_sched_barrier(0);
    // B(kt) DMA already retired by this wave's auto-waitcnt on va(kt);
    // vmcnt(20) = 16 va + 2 DMA + 2 scalars newer than B(kt) (insurance).
    asm volatile("s_waitcnt vmcnt(20)" ::: "memory");
    asm volatile("s_waitcnt lgkmcnt(0)" ::: "memory");
    __builtin_amdgcn_s_barrier();
    __builtin_amdgcn_sched_barrier(0);
    // fragments + MFMA from buf(kt)
    bf16x8 af[2], bfv[4][2];
#pragma unroll
    for (int kk = 0; kk < 2; ++kk) {
      int slotsw = ((kk * 4 + g) ^ (l15 & 7)) * 16;
      af[kk] = *reinterpret_cast<const bf16x8*>(buf + (wm + l15) * 128 + slotsw);
#pragma unroll
      for (int f = 0; f < 4; ++f)
        bfv[f][kk] = *reinterpret_cast<const bf16x8*>(
            buf + 8192 + (f * 16 + l15) * 128 + slotsw);
    }
#pragma unroll
    for (int kk = 0; kk < 2; ++kk)
#pragma unroll
      for (int j = 0; j < 4; ++j)
        acc[j] = __builtin_amdgcn_mfma_f32_16x16x32_bf16(
            af[kk], bfv[j][kk], acc[j], 0, 0, 0);
    a_cur = a_nxt;
    h_cur = h_nxt;
  }
  // fused epilogue: log_pi row-sum over 64 action dims
  float istd[4], cb[4];
#pragma unroll
  for (int j = 0; j < 4; ++j) {
    int n = j * 16 + l15;
    istd[j] = __expf(-log_std[n]);
    cb[j] = Cb[n];
  }
  float sls = 0.f;
  for (int n = 0; n < ADIM; ++n) sls += log_std[n];
  const float cterm = -32.0f * 1.8378770664093453f - sls;
  const int rb = wm + g * 4;
#pragma unroll
  for (int r = 0; r < 4; ++r) {
    int rl = rb + r;                 // local t-row (0..63)
    int mo = (t0 + rl) * 32 + bb;    // original row index [L,B]
    float ss = 0.f;
#pragma unroll
    for (int j = 0; j < 4; ++j) {
      int n = j * 16 + l15;
      float mu = acc[j][r] + cb[j];
      float d = (actions[(size_t)mo * ADIM + n] - mu) * istd[j];
      ss = fmaf(d, d, ss);
    }
    ss += __shfl_xor(ss, 1);
    ss += __shfl_xor(ss, 2);
    ss += __shfl_xor(ss, 4);
    ss += __shfl_xor(ss, 8);
    if (l15 == 0) out[mo] = cterm - 0.5f * ss;
  }
}

// ===================== fallback (round-1 proven, OLD [m][h] layout) ========
__device__ __forceinline__ int swz_fb(int row, int byteInRow) {
  int slot = (byteInRow >> 4) & 3;
  slot = (slot + (row >> 1)) & 3;
  return row * 64 + slot * 16 + (byteInRow & 15);
}

__global__ __launch_bounds__(256) void k_gemm1_fb(
    const float* __restrict__ states, const float* __restrict__ Bw,
    const float* __restrict__ Bb, unsigned short* __restrict__ bout) {
  __shared__ char ldsmem[2 * 128 * 64];
  char* ldsA = ldsmem;
  char* ldsB = ldsmem + 128 * 64;
  const int tid = threadIdx.x;
  const int bx = blockIdx.x;
  const int mt = bx >> 3, nt = bx & 7;
  const int m0 = mt * 128, n0 = nt * 128;
  const int wave = tid >> 6, lane = tid & 63;
  const int wm = (wave >> 1) * 64, wn = (wave & 1) * 64;
  const int sr = tid >> 3;
  const int sc = tid & 7;
  f32x4 acc[4][4];
  for (int i = 0; i < 4; i++)
    for (int j = 0; j < 4; j++) acc[i][j] = (f32x4){0.f, 0.f, 0.f, 0.f};
  const int l15 = lane & 15;
  const int slot16 = (lane >> 4) * 16;
  int offA[4], offB[4], wrOff[4];
  for (int f = 0; f < 4; ++f) {
    offA[f] = swz_fb(wm + f * 16 + l15, slot16);
    offB[f] = swz_fb(wn + f * 16 + l15, slot16);
  }
  for (int p = 0; p < 4; ++p) wrOff[p] = swz_fb(sr + p * 32, sc * 8);
  for (int kt = 0; kt < 8; ++kt) {
    const int k0 = kt * 32;
    for (int p = 0; p < 4; ++p) {
      int r = sr + p * 32;
      float4 va = *reinterpret_cast<const float4*>(states + (size_t)(m0 + r) * SDIM + k0 + sc * 4);
      float4 vb = *reinterpret_cast<const float4*>(Bw + (size_t)(n0 + r) * SDIM + k0 + sc * 4);
      ushort4 wa, wb2;
      wa.x = f2bf(va.x); wa.y = f2bf(va.y); wa.z = f2bf(va.z); wa.w = f2bf(va.w);
      wb2.x = f2bf(vb.x); wb2.y = f2bf(vb.y); wb2.z = f2bf(vb.z); wb2.w = f2bf(vb.w);
      *reinterpret_cast<ushort4*>(ldsA + wrOff[p]) = wa;
      *reinterpret_cast<ushort4*>(ldsB + wrOff[p]) = wb2;
    }
    __syncthreads();
    bf16x8 af[4], bfv[4];
    for (int f = 0; f < 4; ++f) {
      af[f] = *reinterpret_cast<const bf16x8*>(ldsA + offA[f]);
      bfv[f] = *reinterpret_cast<const bf16x8*>(ldsB + offB[f]);
    }
    for (int i = 0; i < 4; ++i)
      for (int j = 0; j < 4; ++j)
        acc[i][j] = __builtin_amdgcn_mfma_f32_16x16x32_bf16(af[i], bfv[j], acc[i][j], 0, 0, 0);
    __syncthreads();
  }
  const int colg = n0 + wn + l15;
  const int rowg = m0 + wm + (lane >> 4) * 4;
  for (int j = 0; j < 4; ++j) {
    float bbv = Bb[colg + j * 16];
    for (int i = 0; i < 4; ++i)
      for (int r = 0; r < 4; ++r) {
        int row = rowg + i * 16 + r;
        bout[(size_t)row * HID + colg + j * 16] = f2bf(acc[i][j][r] + bbv);
      }
  }
}

__global__ __launch_bounds__(256) void k_scan_partial_fb(
    const unsigned short* __restrict__ b, const float* __restrict__ A_log,
    float* __restrict__ Sbuf) {
  int gid = blockIdx.x * 256 + threadIdx.x;
  int ch = (gid & 4095) * 8;
  int c = gid >> 12;
  float4 al0 = *reinterpret_cast<const float4*>(A_log + (ch & (HID - 1)));
  float4 al1 = *reinterpret_cast<const float4*>(A_log + (ch & (HID - 1)) + 4);
  float a[8] = {__expf(al0.x), __expf(al0.y), __expf(al0.z), __expf(al0.w),
                __expf(al1.x), __expf(al1.y), __expf(al1.z), __expf(al1.w)};
  const unsigned short* p = b + (size_t)c * CHUNK * NCH + ch;
  float s[8] = {0.f, 0.f, 0.f, 0.f, 0.f, 0.f, 0.f, 0.f};
#pragma unroll 4
  for (int j = 0; j < CHUNK; ++j) {
    int4 v = *reinterpret_cast<const int4*>(p + (size_t)j * NCH);
    unsigned int u[4] = {(unsigned)v.x, (unsigned)v.y, (unsigned)v.z, (unsigned)v.w};
#pragma unroll
    for (int e = 0; e < 4; ++e) {
      s[2 * e]     = fmaf(a[2 * e],     s[2 * e],     __uint_as_float(u[e] << 16));
      s[2 * e + 1] = fmaf(a[2 * e + 1], s[2 * e + 1], __uint_as_float(u[e] & 0xFFFF0000u));
    }
  }
  float4 o0 = {s[0], s[1], s[2], s[3]}, o1 = {s[4], s[5], s[6], s[7]};
  *reinterpret_cast<float4*>(Sbuf + (size_t)c * NCH + ch) = o0;
  *reinterpret_cast<float4*>(Sbuf + (size_t)c * NCH + ch + 4) = o1;
}

__global__ __launch_bounds__(256) void k_scan_final_fb(
    unsigned short* __restrict__ b, const float* __restrict__ A_log,
    const float* __restrict__ Cbuf) {
  int gid = blockIdx.x * 256 + threadIdx.x;
  int ch = (gid & 4095) * 8;
  int c = gid >> 12;
  float4 al0 = *reinterpret_cast<const float4*>(A_log + (ch & (HID - 1)));
  float4 al1 = *reinterpret_cast<const float4*>(A_log + (ch & (HID - 1)) + 4);
  float a[8] = {__expf(al0.x), __expf(al0.y), __expf(al0.z), __expf(al0.w),
                __expf(al1.x), __expf(al1.y), __expf(al1.z), __expf(al1.w)};
  unsigned short* p = b + (size_t)c * CHUNK * NCH + ch;
  float4 h0 = *reinterpret_cast<const float4*>(Cbuf + (size_t)c * NCH + ch);
  float4 h1 = *reinterpret_cast<const float4*>(Cbuf + (size_t)c * NCH + ch + 4);
  float h[8] = {h0.x, h0.y, h0.z, h0.w, h1.x, h1.y, h1.z, h1.w};
#pragma unroll 2
  for (int j = 0; j < CHUNK; ++j) {
    int4 v = *reinterpret_cast<const int4*>(p + (size_t)j * NCH);
    unsigned int u[4] = {(unsigned)v.x, (unsigned)v.y, (unsigned)v.z, (unsigned)v.w};
    unsigned short ob[8];
#pragma unroll
    for (int e = 0; e < 8; ++e) {
      unsigned int bits = (e & 1) ? (u[e >> 1] & 0xFFFF0000u) : (u[e >> 1] << 16);
      h[e] = fmaf(a[e], h[e], __uint_as_float(bits));
      float ex = __expf(2.0f * h[e]);
      ob[e] = f2bf(1.0f - 2.0f / (ex + 1.0f));
    }
    int4 o;
    o.x = (int)((unsigned)ob[0] | ((unsigned)ob[1] << 16));
    o.y = (int)((unsigned)ob[2] | ((unsigned)ob[3] << 16));
    o.z = (int)((unsigned)ob[4] | ((unsigned)ob[5] << 16));
    o.w = (int)((unsigned)ob[6] | ((unsigned)ob[7] << 16));
    *reinterpret_cast<int4*>(p + (size_t)j * NCH) = o;
  }
}

__global__ __launch_bounds__(256) void k_gemm2_fb(
    const unsigned short* __restrict__ hbuf, const float* __restrict__ actions,
    const float* __restrict__ Cw, const float* __restrict__ Cb,
    const float* __restrict__ log_std, float* __restrict__ out) {
  __shared__ char ldsmem[128 * 64 + 64 * 64];
  char* ldsA = ldsmem;
  char* ldsB = ldsmem + 128 * 64;
  const int tid = threadIdx.x;
  const int m0 = blockIdx.x * 128;
  const int wave = tid >> 6, lane = tid & 63;
  const int wrow = wave * 32;
  const int l15 = lane & 15;
  const int slot16 = (lane >> 4) * 16;
  f32x4 acc[2][4];
  for (int i = 0; i < 2; i++)
    for (int j = 0; j < 4; j++) acc[i][j] = (f32x4){0.f, 0.f, 0.f, 0.f};
  const int cA = tid & 3, rA = tid >> 2;
  const int cB = tid & 7, rB = tid >> 3;
  int offA[2], offB[4], wrA[2], wrB[2];
  for (int f = 0; f < 2; ++f) offA[f] = swz_fb(wrow + f * 16 + l15, slot16);
  for (int f = 0; f < 4; ++f) offB[f] = swz_fb(f * 16 + l15, slot16);
  for (int p = 0; p < 2; ++p) wrA[p] = swz_fb(rA + p * 64, cA * 16);
  for (int p = 0; p < 2; ++p) wrB[p] = swz_fb(rB + p * 32, cB * 8);
  for (int kt = 0; kt < 32; ++kt) {
    int k0 = kt * 32;
    for (int p = 0; p < 2; ++p) {
      int r = rA + p * 64;
      int4 v = *reinterpret_cast<const int4*>(hbuf + (size_t)(m0 + r) * HID + k0 + cA * 8);
      *reinterpret_cast<int4*>(ldsA + wrA[p]) = v;
    }
    for (int p = 0; p < 2; ++p) {
      int r = rB + p * 32;
      float4 v = *reinterpret_cast<const float4*>(Cw + (size_t)r * HID + k0 + cB * 4);
      ushort4 w;
      w.x = f2bf(v.x); w.y = f2bf(v.y); w.z = f2bf(v.z); w.w = f2bf(v.w);
      *reinterpret_cast<ushort4*>(ldsB + wrB[p]) = w;
    }
    __syncthreads();
    bf16x8 af[2], bfv[4];
    for (int f = 0; f < 2; ++f) af[f] = *reinterpret_cast<const bf16x8*>(ldsA + offA[f]);
    for (int f = 0; f < 4; ++f) bfv[f] = *reinterpret_cast<const bf16x8*>(ldsB + offB[f]);
    for (int i = 0; i < 2; ++i)
      for (int j = 0; j < 4; ++j)
        acc[i][j] = __builtin_amdgcn_mfma_f32_16x16x32_bf16(af[i], bfv[j], acc[i][j], 0, 0, 0);
    __syncthreads();
  }
  float istd[4], cb[4];
  for (int j = 0; j < 4; ++j) {
    int n = j * 16 + l15;
    istd[j] = __expf(-log_std[n]);
    cb[j] = Cb[n];
  }
  float sls = 0.f;
  for (int n = 0; n < 64; ++n) sls += log_std[n];
  const float cterm = -32.0f * 1.8378770664093453f - sls;
  const int rbase = m0 + wrow + (lane >> 4) * 4;
  for (int i = 0; i < 2; ++i)
    for (int r = 0; r < 4; ++r) {
      int row = rbase + i * 16 + r;
      float ss = 0.f;
      for (int j = 0; j < 4; ++j) {
        int n = j * 16 + l15;
        float mu = acc[i][j][r] + cb[j];
        float d = (actions[(size_t)row * ADIM + n] - mu) * istd[j];
        ss = fmaf(d, d, ss);
      }
      ss += __shfl_xor(ss, 1);
      ss += __shfl_xor(ss, 2);
      ss += __shfl_xor(ss, 4);
      ss += __shfl_xor(ss, 8);
      if (l15 == 0) out[row] = cterm - 0.5f * ss;
    }
}

extern "C" void kernel_launch(void* const* d_in, const int* in_sizes, int n_in,
                              void* d_out, int out_size, void* d_ws, size_t ws_size,
                              hipStream_t stream) {
  const float* states  = (const float*)d_in[0];
  const float* actions = (const float*)d_in[1];
  const float* A_log   = (const float*)d_in[2];
  const float* B_w     = (const float*)d_in[3];
  const float* B_b     = (const float*)d_in[4];
  const float* C_w     = (const float*)d_in[5];
  const float* C_b     = (const float*)d_in[6];
  const float* log_std = (const float*)d_in[7];
  float* out = (float*)d_out;
  char* ws = (char*)d_ws;

  unsigned short* bbuf = (unsigned short*)ws;
  float* Sbuf = (float*)(ws + WS_SBUF);
  float* Cbuf = (float*)(ws + WS_CBUF);
  const int scan_grid = NCHUNK * 4096 / 256;  // 2048 blocks

  if (ws_size >= WS_NEED) {
    unsigned short* stb = (unsigned short*)(ws + WS_STB);
    unsigned short* bwb = (unsigned short*)(ws + WS_BWB);
    unsigned short* cwb = (unsigned short*)(ws + WS_CWB);
    k_cvt<<<8352, 256, 0, stream>>>(states, B_w, C_w, stb, bwb, cwb);
    k_gemm1p<<<4096, 256, 0, stream>>>(stb, bwb, B_b, bbuf);
    k_scan_partial<<<scan_grid, 256, 0, stream>>>(bbuf, A_log, Sbuf);
    k_scan_carry<<<128, 256, 0, stream>>>(Sbuf, A_log, Cbuf);
    k_gemm2f<<<1024, 256, 0, stream>>>(bbuf, actions, cwb, C_b, log_std, A_log,
                                       Cbuf, out);
  } else {
    k_gemm1_fb<<<4096, 256, 0, stream>>>(states, B_w, B_b, bbuf);
    k_scan_partial_fb<<<scan_grid, 256, 0, stream>>>(bbuf, A_log, Sbuf);
    k_scan_carry<<<128, 256, 0, stream>>>(Sbuf, A_log, Cbuf);
    k_scan_final_fb<<<scan_grid, 256, 0, stream>>>(bbuf, A_log, Cbuf);
    k_gemm2_fb<<<512, 256, 0, stream>>>(bbuf, actions, C_w, C_b, log_std, out);
  }
}